// Round 13
// baseline (197.321 us; speedup 1.0000x reference)
//
#include <hip/hip_runtime.h>
#include <stdint.h>
#include <limits.h>

// ---------------------------------------------------------------------------
// RPN loss, bit-exact replication of the JAX reference (incl. threefry PRNG).
// Round 13: SPATIAL BINNING. r12's inter>0 guard failed because anchors are
// random boxes -> 64 lanes spatially independent -> P(any lane hits) ~ 99%
// -> no execz skip. Fix: bin anchors by center into 16x16 cells of 64px
// (asort permutation + ainv inverse, built by 2 tiny kernels).
//  - best path: per gt, iterate only cells with center in [gt-129, gt+129]
//    (129 > max anchor half-extent 128 -> conservative). Packed (iou,~a)
//    max with init (0,~0) == reference argmax incl. all-zero -> index 0.
//  - label path: blocks process 256 SORTED positions (co-located anchors);
//    union-bbox staging of candidate gts (~20 of 128); tie-break
//    (v>bv)||(v==bv&&g<bi) == reference first-occurrence argmax.
// All stores coalesced (position-indexed); downstream uses asort[pos] for
// original indices (rank tie-breaks on ORIGINAL index = reference).
// Rule from r3/r4 stands: no cross-thread communication inside inner loops.
// ---------------------------------------------------------------------------
#define PARTITIONABLE 1

#define B_ 8
#define K_ 9
#define H_ 64
#define W_ 64
#define G_ 128
#define A_ 36864            // K*H*W
#define HALF_A 18432
#define NBUCK 8192          // buckets over 23-bit v (v>>10)
#define CAP 1024            // cutoff-bucket candidate capacity (expected ~5)
#define NCX 16
#define NCELL 256           // 16x16 cells of 64 px
#define NBEST2 2048         // best blocks: 1024 gt-rows x 2 (cy parity)
#define NLAB  1152          // label blocks (144 x 8)

struct KeyParams { uint32_t k[B_][4]; };   // per image: k1.(0,1), k2.(0,1)

__host__ __device__ static inline uint32_t rotl32(uint32_t x, int r) {
  return (x << r) | (x >> (32 - r));
}

// JAX threefry2x32: 20 rounds, key injections every 4 rounds.
__host__ __device__ static inline void tf2x32(uint32_t k0, uint32_t k1,
                                              uint32_t x0, uint32_t x1,
                                              uint32_t& o0, uint32_t& o1) {
  uint32_t ks2 = k0 ^ k1 ^ 0x1BD11BDAu;
  x0 += k0; x1 += k1;
#define TF_R(r) { x0 += x1; x1 = rotl32(x1, r); x1 ^= x0; }
  TF_R(13) TF_R(15) TF_R(26) TF_R(6)
  x0 += k1;  x1 += ks2 + 1u;
  TF_R(17) TF_R(29) TF_R(16) TF_R(24)
  x0 += ks2; x1 += k0 + 2u;
  TF_R(13) TF_R(15) TF_R(26) TF_R(6)
  x0 += k0;  x1 += k1 + 3u;
  TF_R(17) TF_R(29) TF_R(16) TF_R(24)
  x0 += k1;  x1 += ks2 + 4u;
  TF_R(13) TF_R(15) TF_R(26) TF_R(6)
  x0 += ks2; x1 += k0 + 5u;
#undef TF_R
  o0 = x0; o1 = x1;
}

// 23-bit sort key of jax.random.uniform(key,(A,))[a] (ORIGINAL anchor index).
__device__ static inline uint32_t anchor_vbits(uint32_t k0, uint32_t k1, int a) {
  uint32_t o0, o1;
#if PARTITIONABLE
  tf2x32(k0, k1, 0u, (uint32_t)a, o0, o1);
  return (o0 ^ o1) >> 9;
#else
  if (a < HALF_A) { tf2x32(k0, k1, (uint32_t)a, (uint32_t)(a + HALF_A), o0, o1); return o0 >> 9; }
  else            { tf2x32(k0, k1, (uint32_t)(a - HALF_A), (uint32_t)a, o0, o1); return o1 >> 9; }
#endif
}

// Box area, contraction off (bit-identical to XLA's plain fp32 ops).
__device__ static inline float area_of(float x0, float y0, float x1, float y1) {
#pragma clang fp contract(off)
  return (x1 - x0) * (y1 - y0);
}

// Intersection area only (cheap prefilter; exact, clamped >= 0).
__device__ static inline float inter_of(float a0, float a1, float a2, float a3,
                                        float g0, float g1, float g2, float g3) {
#pragma clang fp contract(off)
  float ltx = fmaxf(a0, g0), lty = fmaxf(a1, g1);
  float rbx = fminf(a2, g2), rby = fminf(a3, g3);
  float w = rbx - ltx; w = (w < 0.f) ? 0.f : w;
  float h = rby - lty; h = (h < 0.f) ? 0.f : h;
  return w * h;
}

// Exact IoU tail, same op order as reference: inter/(area_a+area_g-inter+1e-6).
__device__ static inline float iou_div(float inter, float area_a, float area_g) {
#pragma clang fp contract(off)
  return inter / (area_a + area_g - inter + 1e-6f);
}

__device__ static inline void encode4(float4 an, float4 gg, float* tt) {
#pragma clang fp contract(off)
  float aw  = an.z - an.x,            ah  = an.w - an.y;
  float acx = (an.x + an.z) * 0.5f,   acy = (an.y + an.w) * 0.5f;
  float gw  = gg.z - gg.x,            gh  = gg.w - gg.y;
  float gcx = (gg.x + gg.z) * 0.5f,   gcy = (gg.y + gg.w) * 0.5f;
  tt[0] = (gcx - acx) / aw;
  tt[1] = (gcy - acy) / ah;
  tt[2] = logf(gw / aw);
  tt[3] = logf(gh / ah);
}

__device__ static inline int cell_of(float4 an) {
  float cx = (an.x + an.z) * 0.5f;
  float cy = (an.y + an.w) * 0.5f;
  int ix = (int)floorf(cx * (1.0f / 64.0f));
  int iy = (int)floorf(cy * (1.0f / 64.0f));
  ix = ix < 0 ? 0 : (ix > 15 ? 15 : ix);
  iy = iy < 0 ? 0 : (iy > 15 ? 15 : iy);
  return iy * NCX + ix;
}

__device__ static inline int block_reduce_int(int v, int* sh) {
  int t = threadIdx.x;
  sh[t] = v; __syncthreads();
  for (int s = 128; s > 0; s >>= 1) { if (t < s) sh[t] += sh[t + s]; __syncthreads(); }
  int r = sh[0]; __syncthreads();
  return r;
}
__device__ static inline float block_reduce_float(float v, float* sh) {
  int t = threadIdx.x;
  sh[t] = v; __syncthreads();
  for (int s = 128; s > 0; s >>= 1) { if (t < s) sh[t] += sh[t + s]; __syncthreads(); }
  float r = sh[0]; __syncthreads();
  return r;
}

__device__ static inline unsigned long long pack_vi(float v, int a) {
  return ((unsigned long long)__float_as_uint(v) << 32) | (uint32_t)(~(uint32_t)a);
}

// K0a: count anchors per cell.
__global__ __launch_bounds__(256) void bin_count_k(const float* __restrict__ anchors,
                                                   int* __restrict__ bcount) {
  int a = blockIdx.x * 256 + threadIdx.x;   // < A_ exactly (144 blocks)
  atomicAdd(&bcount[cell_of(((const float4*)anchors)[a])], 1);
}

// K0b: scatter into bin-sorted order; every block recomputes the prefix.
__global__ __launch_bounds__(256) void bin_scatter_k(const float* __restrict__ anchors,
                                                     const int* __restrict__ bcount,
                                                     int* __restrict__ bcur,
                                                     int* __restrict__ asort,
                                                     int* __restrict__ ainv) {
  __shared__ int cnt[NCELL];
  __shared__ int tmp[NCELL];
  const int t = threadIdx.x;
  cnt[t] = bcount[t];
  tmp[t] = cnt[t];
  __syncthreads();
  for (int off = 1; off < NCELL; off <<= 1) {       // inclusive scan
    int v = (t >= off) ? tmp[t - off] : 0;
    __syncthreads();
    tmp[t] += v;
    __syncthreads();
  }
  int a = blockIdx.x * 256 + t;
  int c = cell_of(((const float4*)anchors)[a]);
  int base = tmp[c] - cnt[c];                       // exclusive prefix
  int pos = base + atomicAdd(&bcur[c], 1);
  asort[pos] = a;
  ainv[a] = pos;
}

// K1 (fused): bid < NBEST2 -> per (gt, cy-parity): argmax over candidate-cell
//             anchors only. bid >= NBEST2 -> label path over sorted positions
//             with block-staged candidate gts.
__global__ __launch_bounds__(256) void fused_iou_k(const float* __restrict__ anchors,
                                                   const float* __restrict__ gtb,
                                                   const int* __restrict__ bcount,
                                                   const int* __restrict__ asort,
                                                   int* __restrict__ labels,
                                                   int* __restrict__ mgt,
                                                   uint32_t* __restrict__ vpos,
                                                   uint32_t* __restrict__ vneg,
                                                   int* __restrict__ ghist,
                                                   int* __restrict__ counts,
                                                   unsigned long long* __restrict__ gmax,
                                                   KeyParams kp) {
  const int bid = blockIdx.x;
  const int t = threadIdx.x;

  if (bid < NBEST2) {
    // ------------------------- best-anchor path ----------------------------
    __shared__ int tmp[NCELL];
    __shared__ int est[NCELL + 1];                 // exclusive prefix + sentinel
    __shared__ unsigned long long sp[256];
    tmp[t] = bcount[t];
    __syncthreads();
    for (int off = 1; off < NCELL; off <<= 1) {
      int v = (t >= off) ? tmp[t - off] : 0;
      __syncthreads();
      tmp[t] += v;
      __syncthreads();
    }
    est[t + 1] = tmp[t];
    if (t == 0) est[0] = 0;
    __syncthreads();

    const int bg = bid >> 1;                       // b*G + g
    const int par = bid & 1;                       // cy parity split
    float4 gg = ((const float4*)gtb)[bg];
    const float area_g = area_of(gg.x, gg.y, gg.z, gg.w);
    // candidate cells: any anchor with center outside cannot intersect
    // (half-extent <= 128 < 129, incl. rounding slack).
    int cxlo = (int)floorf((gg.x - 129.f) * (1.f / 64.f));
    int cxhi = (int)floorf((gg.z + 129.f) * (1.f / 64.f));
    int cylo = (int)floorf((gg.y - 129.f) * (1.f / 64.f));
    int cyhi = (int)floorf((gg.w + 129.f) * (1.f / 64.f));
    cxlo = cxlo < 0 ? 0 : cxlo;  cxhi = cxhi > 15 ? 15 : cxhi;
    cylo = cylo < 0 ? 0 : cylo;  cyhi = cyhi > 15 ? 15 : cyhi;

    unsigned long long p = pack_vi(0.f, 0);        // all-zero -> anchor 0
    for (int cy = cylo; cy <= cyhi; cy++) {
      if (((cy - cylo) & 1) != par) continue;
      const int beg = est[cy * NCX + cxlo];
      const int end = est[cy * NCX + cxhi + 1];    // row-contiguous span
      for (int pos = beg + t; pos < end; pos += 256) {
        int aidx = asort[pos];
        float4 an = ((const float4*)anchors)[aidx];
        float inter = inter_of(an.x, an.y, an.z, an.w, gg.x, gg.y, gg.z, gg.w);
        if (inter > 0.f) {
          float v = iou_div(inter, area_of(an.x, an.y, an.z, an.w), area_g);
          unsigned long long q = pack_vi(v, aidx);
          if (q > p) p = q;                        // (higher iou, smaller a)
        }
      }
    }
    sp[t] = p; __syncthreads();
    for (int s = 128; s > 0; s >>= 1) {
      if (t < s) { if (sp[t + s] > sp[t]) sp[t] = sp[t + s]; }
      __syncthreads();
    }
    if (t == 0) atomicMax(&gmax[bg], sp[0]);       // no-return, once/block
    return;
  }

  // --------------------------- label path ----------------------------------
  __shared__ float rf[256];
  __shared__ float4 sg[G_];
  __shared__ int sgid[G_];
  __shared__ int ns;
  __shared__ int red[256];
  const int r = bid - NBEST2;
  const int b = r / (A_ / 256);
  const int xb = r % (A_ / 256);
  const int posn = xb * 256 + t;                   // sorted position < A_
  const int aidx = asort[posn];                    // original anchor index
  float4 an = ((const float4*)anchors)[aidx];

  // block union-bbox of anchor boxes (4 reductions)
  rf[t] = an.x; __syncthreads();
  for (int s = 128; s > 0; s >>= 1) { if (t < s) rf[t] = fminf(rf[t], rf[t + s]); __syncthreads(); }
  float xmin = rf[0]; __syncthreads();
  rf[t] = an.y; __syncthreads();
  for (int s = 128; s > 0; s >>= 1) { if (t < s) rf[t] = fminf(rf[t], rf[t + s]); __syncthreads(); }
  float ymin = rf[0]; __syncthreads();
  rf[t] = an.z; __syncthreads();
  for (int s = 128; s > 0; s >>= 1) { if (t < s) rf[t] = fmaxf(rf[t], rf[t + s]); __syncthreads(); }
  float xmax = rf[0]; __syncthreads();
  rf[t] = an.w; __syncthreads();
  for (int s = 128; s > 0; s >>= 1) { if (t < s) rf[t] = fmaxf(rf[t], rf[t + s]); __syncthreads(); }
  float ymax = rf[0];
  if (t == 0) ns = 0;
  __syncthreads();

  // stage candidate gts: any gt overlapping the union bbox (conservative).
  if (t < G_) {
    float4 gg = ((const float4*)gtb)[b * G_ + t];
    if (gg.x <= xmax && gg.z >= xmin && gg.y <= ymax && gg.w >= ymin) {
      int q = atomicAdd(&ns, 1);
      sg[q] = gg; sgid[q] = t;
    }
  }
  __syncthreads();
  const int nss = ns;

  float area_a = area_of(an.x, an.y, an.z, an.w);
  float bv = 0.f; int bi = 0;                      // all-zero row -> g=0
  for (int j = 0; j < nss; j++) {
    float4 gg = sg[j]; int g = sgid[j];
    float inter = inter_of(an.x, an.y, an.z, an.w, gg.x, gg.y, gg.z, gg.w);
    if (inter > 0.f) {
      float v = iou_div(inter, area_a, area_of(gg.x, gg.y, gg.z, gg.w));
      // order-free first-occurrence argmax: (max v, then smallest g)
      if (v > bv || (v == bv && g < bi)) { bv = v; bi = g; }
    }
  }
  int lb = (bv < 0.3f) ? 0 : ((bv >= 0.7f) ? 1 : -1);
  size_t idx = (size_t)b * A_ + posn;              // position-indexed arrays
  uint32_t vp = anchor_vbits(kp.k[b][0], kp.k[b][1], aidx);
  uint32_t vn = anchor_vbits(kp.k[b][2], kp.k[b][3], aidx);
  labels[idx] = lb;
  mgt[idx]    = bi;
  vpos[idx]   = vp;
  vneg[idx]   = vn;
  if (lb == 1)      atomicAdd(&ghist[(b * 2 + 0) * NBUCK + (vp >> 10)], 1);
  else if (lb == 0) atomicAdd(&ghist[(b * 2 + 1) * NBUCK + (vn >> 10)], 1);
  int packed = (lb == 1 ? 1 : 0) | ((lb == 0 ? 1 : 0) << 16);
  int rr = block_reduce_int(packed, red);
  if (t == 0) {
    atomicAdd(&counts[b * 2 + 0], rr & 0xFFFF);
    atomicAdd(&counts[b * 2 + 1], rr >> 16);
  }
}

// K2: force best anchor per gt to 1 (via ainv); patch counts + histograms.
__global__ void force_k(const unsigned long long* __restrict__ gmax,
                        const int* __restrict__ ainv,
                        int* __restrict__ labels,
                        const uint32_t* __restrict__ vpos,
                        const uint32_t* __restrict__ vneg,
                        int* __restrict__ ghist,
                        int* __restrict__ counts) {
  int tg = blockIdx.x * 256 + threadIdx.x;   // < B_*G_ exactly (4 blocks)
  int b = tg / G_;
  int a = (int)(~(uint32_t)(gmax[tg] & 0xFFFFFFFFull));   // original index
  int posn = ainv[a];
  size_t idx = (size_t)b * A_ + posn;
  int old = atomicExch(&labels[idx], 1);
  if (old != 1) {
    atomicAdd(&counts[b * 2 + 0], 1);
    atomicAdd(&ghist[(b * 2 + 0) * NBUCK + (vpos[idx] >> 10)], 1);
    if (old == 0) {
      atomicSub(&counts[b * 2 + 1], 1);
      atomicSub(&ghist[(b * 2 + 1) * NBUCK + (vneg[idx] >> 10)], 1);
    }
  }
}

// K3: per (b,c): target + exact cutoff bucket cb and in-bucket remainder R.
__global__ __launch_bounds__(256) void cutoff_k(const int* __restrict__ ghist,
                                                const int* __restrict__ counts,
                                                int* __restrict__ cbR,
                                                int* __restrict__ targets) {
  const int row = blockIdx.x;               // b*2 + c
  const int b = row >> 1, c = row & 1;
  const int t = threadIdx.x;
  __shared__ int seg[256];
  int npos = counts[b * 2 + 0], nneg = counts[b * 2 + 1];
  int tp = npos < 128 ? npos : 128;
  int tn = 256 - tp; if (nneg < tn) tn = nneg;
  const int target = (c == 0) ? tp : tn;
  const int* hist = ghist + (size_t)row * NBUCK;
  { int s = 0; const int base = t * 32;
    for (int i = 0; i < 32; i++) s += hist[base + i];
    seg[t] = s; }
  __syncthreads();
  if (t == 0) {
    int cb = INT_MAX, R = 0;
    if (target > 0) {
      int cum = 0, si = -1;
      for (int i = 255; i >= 0; i--) { if (cum + seg[i] >= target) { si = i; break; } cum += seg[i]; }
      for (int j = si * 32 + 31; j >= si * 32; j--) {
        if (cum + hist[j] >= target) { cb = j; R = target - cum; break; }
        cum += hist[j];
      }
    }
    cbR[row * 2 + 0] = cb;
    cbR[row * 2 + 1] = R;
    targets[row] = target;
  }
}

// K4: gather cutoff-bucket candidates; cii stores ORIGINAL anchor index
// (rank tie-breaks must use reference ordering).
__global__ __launch_bounds__(256) void cand_k(const int* __restrict__ labels,
                                              const uint32_t* __restrict__ vpos,
                                              const uint32_t* __restrict__ vneg,
                                              const int* __restrict__ asort,
                                              const int* __restrict__ cbR,
                                              int* __restrict__ ccnt,
                                              uint32_t* __restrict__ cvv,
                                              int* __restrict__ cii) {
  const int b = blockIdx.y;
  const int posn = blockIdx.x * 256 + threadIdx.x;
  size_t idx = (size_t)b * A_ + posn;
  int lb = labels[idx];
  if (lb < 0) return;
  int c = (lb == 1) ? 0 : 1;
  int row = b * 2 + c;
  uint32_t v = (c == 0 ? vpos : vneg)[idx];
  if ((int)(v >> 10) == cbR[row * 2]) {
    int p = atomicAdd(&ccnt[row], 1);
    if (p < CAP) { cvv[row * CAP + p] = v; cii[row * CAP + p] = asort[posn]; }
  }
}

// K5: distributed loss pass over positions; rank tie-break on ORIGINAL index.
__global__ __launch_bounds__(256) void loss_k(const float* __restrict__ anchors,
                                              const float* __restrict__ gtb,
                                              const float* __restrict__ cls,
                                              const float* __restrict__ boxp,
                                              const int* __restrict__ labels,
                                              const int* __restrict__ mgt,
                                              const uint32_t* __restrict__ vpos,
                                              const uint32_t* __restrict__ vneg,
                                              const int* __restrict__ asort,
                                              const int* __restrict__ cbR,
                                              const int* __restrict__ ccnt,
                                              const uint32_t* __restrict__ cvv,
                                              const int* __restrict__ cii,
                                              float* __restrict__ bsums) {
  const int b = blockIdx.y;
  const int posn = blockIdx.x * 256 + threadIdx.x;
  const int t = threadIdx.x;
  __shared__ float redf[256];
  float sb = 0.f, ss = 0.f;
  size_t idx = (size_t)b * A_ + posn;
  int lb = labels[idx];
  if (lb >= 0) {
    int c = (lb == 1) ? 0 : 1;
    int row = b * 2 + c;
    uint32_t v = (c == 0 ? vpos : vneg)[idx];
    int bucket = (int)(v >> 10);
    int cb = cbR[row * 2];
    int a = asort[posn];                     // original anchor index
    bool kept = bucket > cb;                 // cb==INT_MAX -> never
    if (!kept && bucket == cb) {
      int c2 = ccnt[row]; if (c2 > CAP) c2 = CAP;
      int R = cbR[row * 2 + 1];
      int rk = 0;
      for (int j = 0; j < c2; j++) {
        uint32_t vj = cvv[row * CAP + j]; int ij = cii[row * CAP + j];
        if (vj > v || (vj == v && ij < a)) rk++;
      }
      kept = (rk < R);
    }
    if (kept) {
      int a2 = asort[posn];
      int kk = a2 % K_; int hw = a2 / K_; int hh = hw / W_; int wx = hw % W_;
      float x  = cls[(((size_t)b * K_ + kk) * H_ + hh) * W_ + wx];
      float sp = fmaxf(x, 0.f) + log1pf(expf(-fabsf(x)));   // logaddexp(x,0)
      sb = (lb == 1) ? (sp - x) : sp;
      if (lb == 1) {
        float4 an = ((const float4*)anchors)[a2];
        int    mg = mgt[idx];
        float4 gg = ((const float4*)gtb)[b * G_ + mg];
        float tt[4]; encode4(an, gg, tt);
        for (int cc = 0; cc < 4; cc++) {
          float p = boxp[(((size_t)b * (4 * K_) + (4 * kk + cc)) * H_ + hh) * W_ + wx];
          float d = p - tt[cc];
          float ad = fabsf(d);
          ss += (ad < 1.f) ? (0.5f * d * d) : (ad - 0.5f);
        }
      }
    }
  }
  float sbT = block_reduce_float(sb, redf);
  float ssT = block_reduce_float(ss, redf);
  if (t == 0) {
    if (sbT != 0.f) atomicAdd(&bsums[b * 2 + 0], sbT);
    if (ssT != 0.f) atomicAdd(&bsums[b * 2 + 1], ssT);
  }
}

// K6: combine per-image sums into the 3 outputs.
__global__ void final_k(const float* __restrict__ bsums, const int* __restrict__ targets,
                        float* __restrict__ out) {
  if (threadIdx.x == 0 && blockIdx.x == 0) {
    float cl = 0.f, bl = 0.f;
    for (int b = 0; b < B_; b++) {
      int tp = targets[b * 2 + 0], tn = targets[b * 2 + 1];
      cl += bsums[b * 2 + 0] / fmaxf((float)(tp + tn), 1.f);
      bl += bsums[b * 2 + 1] / fmaxf(4.f * (float)tp, 1.f);
    }
    cl *= 0.125f; bl *= 0.125f;
    out[0] = cl; out[1] = bl; out[2] = cl + bl;
  }
}

static void compute_keys(KeyParams& kp) {
  const uint32_t r0 = 0u, r1 = 42u;        // jax.random.key(42) -> (hi, lo)
#if PARTITIONABLE
  for (int b = 0; b < B_; b++) {
    uint32_t kb0, kb1;
    tf2x32(r0, r1, 0u, (uint32_t)b, kb0, kb1);        // split(root, 8)[b]
    uint32_t a0, a1, c0, c1;
    tf2x32(kb0, kb1, 0u, 0u, a0, a1);                 // split(key)[0] = k1
    tf2x32(kb0, kb1, 0u, 1u, c0, c1);                 // split(key)[1] = k2
    kp.k[b][0] = a0; kp.k[b][1] = a1; kp.k[b][2] = c0; kp.k[b][3] = c1;
  }
#else
  uint32_t o0[8], o1[8], flat[16];
  for (int i = 0; i < 8; i++) tf2x32(r0, r1, (uint32_t)i, (uint32_t)(8 + i), o0[i], o1[i]);
  for (int i = 0; i < 8; i++) { flat[i] = o0[i]; flat[8 + i] = o1[i]; }
  for (int b = 0; b < B_; b++) {
    uint32_t kb0 = flat[2 * b], kb1 = flat[2 * b + 1];
    uint32_t a0, b0, a1, b1;
    tf2x32(kb0, kb1, 0u, 2u, a0, b0);
    tf2x32(kb0, kb1, 1u, 3u, a1, b1);
    kp.k[b][0] = a0; kp.k[b][1] = a1; kp.k[b][2] = b0; kp.k[b][3] = b1;
  }
#endif
}

extern "C" void kernel_launch(void* const* d_in, const int* in_sizes, int n_in,
                              void* d_out, int out_size, void* d_ws, size_t ws_size,
                              hipStream_t stream) {
  const float* cls     = (const float*)d_in[0];   // [B,K,H,W]
  const float* boxp    = (const float*)d_in[1];   // [B,4K,H,W]
  const float* anchors = (const float*)d_in[2];   // [A,4]
  const float* gtb     = (const float*)d_in[3];   // [B,G,4]
  float* out = (float*)d_out;

  uint8_t* w = (uint8_t*)d_ws;
  // zeroed region [0, 534720):
  unsigned long long* gmax = (unsigned long long*)w;    // [0,8192)       B*G u64
  int*      ghist   = (int*)(w + 8192);                 // [8192,532480)  16*NBUCK
  int*      counts  = (int*)(w + 532480);               // [532480,532544)
  int*      ccnt    = (int*)(w + 532544);               // [532544,532608)
  float*    bsums   = (float*)(w + 532608);             // [532608,532672)
  int*      bcount  = (int*)(w + 532672);               // [532672,533696) 256 ints
  int*      bcur    = (int*)(w + 533696);               // [533696,534720) 256 ints
  // non-zeroed region (sequential bumps from 534720):
  int*      labels  = (int*)(w + 534720);               // B*A
  int*      mgt     = labels + (size_t)B_ * A_;         // B*A
  uint32_t* vpos    = (uint32_t*)(mgt + (size_t)B_ * A_);  // B*A
  uint32_t* vneg    = vpos + (size_t)B_ * A_;           // B*A
  int*      asort   = (int*)(vneg + (size_t)B_ * A_);   // A
  int*      ainv    = asort + A_;                       // A
  int*      cbR     = ainv + A_;                        // 32
  int*      targets = cbR + 32;                         // 16
  uint32_t* cvv     = (uint32_t*)(targets + 16);        // 16*CAP
  int*      cii     = (int*)(cvv + 16 * CAP);           // 16*CAP

  KeyParams kp;
  compute_keys(kp);

  (void)hipMemsetAsync(w, 0, 534720, stream);
  bin_count_k<<<A_ / 256, 256, 0, stream>>>(anchors, bcount);
  bin_scatter_k<<<A_ / 256, 256, 0, stream>>>(anchors, bcount, bcur, asort, ainv);
  fused_iou_k<<<NBEST2 + NLAB, 256, 0, stream>>>(anchors, gtb, bcount, asort,
                                                 labels, mgt, vpos, vneg,
                                                 ghist, counts, gmax, kp);
  force_k<<<(B_ * G_) / 256, 256, 0, stream>>>(gmax, ainv, labels, vpos, vneg,
                                               ghist, counts);
  cutoff_k<<<16, 256, 0, stream>>>(ghist, counts, cbR, targets);
  cand_k<<<dim3(A_ / 256, B_), 256, 0, stream>>>(labels, vpos, vneg, asort, cbR,
                                                 ccnt, cvv, cii);
  loss_k<<<dim3(A_ / 256, B_), 256, 0, stream>>>(anchors, gtb, cls, boxp, labels, mgt,
                                                 vpos, vneg, asort, cbR, ccnt, cvv, cii,
                                                 bsums);
  final_k<<<1, 64, 0, stream>>>(bsums, targets, out);
}